// Round 2
// baseline (135.433 us; speedup 1.0000x reference)
//
#include <hip/hip_runtime.h>
#include <math.h>

#define TOKENS 16384
#define HIDDEN 2048
#define NEXP   64
#define MBLK   16                 // tokens per block
#define KBLK   16                 // k per staged tile
#define NWAVE  4
#define KCH    (HIDDEN / NWAVE)   // 512 per wave
#define NTILE  (KCH / KBLK)       // 32
#define RPAD   20                 // row stride in floats (16B aligned)
#define TOPK   6
#define NGROUP 8
#define TOPKG  3

__global__ __launch_bounds__(256, 4)
void moe_gate_kernel(const float* __restrict__ X, const float* __restrict__ W,
                     float* __restrict__ out, int half_out)
{
    __shared__ float xs[NWAVE][MBLK][RPAD];   // 4*16*20*4 = 5120 B
    __shared__ float wl[NWAVE][NEXP][RPAD];   // 4*64*20*4 = 20480 B
    __shared__ float red[MBLK][NEXP + 1];     // 16*65*4  = 4160 B  (~29.8 KB)

    const int tid  = threadIdx.x;
    const int wv   = tid >> 6;        // wave 0..3 owns a K chunk
    const int lane = tid & 63;
    const int lr   = lane >> 3;       // 0..7 token-row group
    const int lc   = lane & 7;        // 0..7 expert-col group
    const int row0 = blockIdx.x * MBLK;
    const int kb0  = wv * KCH;

    // staging lane mapping: 4 lanes per row, float4 each (16 k = 4 float4)
    const int sr = lane >> 2;         // 0..15
    const int sc = lane & 3;          // 0..3

    float acc[2][8];
#pragma unroll
    for (int i = 0; i < 2; ++i)
#pragma unroll
        for (int j = 0; j < 8; ++j) acc[i][j] = 0.f;

    const float* xb = X + (size_t)row0 * HIDDEN + kb0;
    const float* wb = W + kb0;

    float4 px;        // x tile: 16 rows x 16 k = 64 float4 = 1 instr
    float4 pw[4];     // w tile: 64 rows x 16 k = 256 float4 = 4 instrs

    // ---- prologue: prefetch tile 0
    px = *(const float4*)(xb + (size_t)sr * HIDDEN + sc * 4);
#pragma unroll
    for (int it = 0; it < 4; ++it) {
        int r = it * 16 + sr;
        pw[it] = *(const float4*)(wb + (size_t)r * HIDDEN + sc * 4);
    }

    for (int t = 0; t < NTILE; ++t) {
        // store prefetched tile to LDS
        {
            float* dx = &xs[wv][sr][sc * 4];
            dx[0] = px.x; dx[1] = px.y; dx[2] = px.z; dx[3] = px.w;
#pragma unroll
            for (int it = 0; it < 4; ++it) {
                float* dw = &wl[wv][it * 16 + sr][sc * 4];
                dw[0] = pw[it].x; dw[1] = pw[it].y; dw[2] = pw[it].z; dw[3] = pw[it].w;
            }
        }
        __syncthreads();

        // prefetch tile t+1 (overlaps with compute)
        if (t + 1 < NTILE) {
            const float* xt = xb + (t + 1) * KBLK;
            const float* wt = wb + (t + 1) * KBLK;
            px = *(const float4*)(xt + (size_t)sr * HIDDEN + sc * 4);
#pragma unroll
            for (int it = 0; it < 4; ++it) {
                int r = it * 16 + sr;
                pw[it] = *(const float4*)(wt + (size_t)r * HIDDEN + sc * 4);
            }
        }

        // compute: 4 k-groups of 4, float4 LDS reads
#pragma unroll
        for (int k4 = 0; k4 < KBLK / 4; ++k4) {
            float4 a[2], b[8];
#pragma unroll
            for (int i = 0; i < 2; ++i)
                a[i] = *(const float4*)&xs[wv][i * 8 + lr][k4 * 4];
#pragma unroll
            for (int j = 0; j < 8; ++j)
                b[j] = *(const float4*)&wl[wv][j * 8 + lc][k4 * 4];
#pragma unroll
            for (int i = 0; i < 2; ++i)
#pragma unroll
                for (int j = 0; j < 8; ++j) {
                    acc[i][j] = fmaf(a[i].x, b[j].x, acc[i][j]);
                    acc[i][j] = fmaf(a[i].y, b[j].y, acc[i][j]);
                    acc[i][j] = fmaf(a[i].z, b[j].z, acc[i][j]);
                    acc[i][j] = fmaf(a[i].w, b[j].w, acc[i][j]);
                }
        }
        __syncthreads();
    }

    // ---- deterministic cross-wave reduction: wave order 0,1,2,3
    if (wv == 0) {
#pragma unroll
        for (int i = 0; i < 2; ++i)
#pragma unroll
            for (int j = 0; j < 8; ++j)
                red[i * 8 + lr][j * 8 + lc] = acc[i][j];
    }
    __syncthreads();
    for (int v = 1; v < NWAVE; ++v) {
        if (wv == v) {
#pragma unroll
            for (int i = 0; i < 2; ++i)
#pragma unroll
                for (int j = 0; j < 8; ++j)
                    red[i * 8 + lr][j * 8 + lc] += acc[i][j];
        }
        __syncthreads();
    }

    // ---- routing: one lane per token (threads 0..15)
    if (tid < MBLK) {
        const int t = tid;
        float s[NEXP];
        float m = -INFINITY;
#pragma unroll
        for (int e = 0; e < NEXP; ++e) { s[e] = red[t][e]; m = fmaxf(m, s[e]); }
        float sum = 0.f;
#pragma unroll
        for (int e = 0; e < NEXP; ++e) { s[e] = __expf(s[e] - m); sum += s[e]; }
        float inv = 1.f / sum;
#pragma unroll
        for (int e = 0; e < NEXP; ++e) s[e] *= inv;

        // group maxes (8 groups of 8)
        float gs[NGROUP];
#pragma unroll
        for (int g = 0; g < NGROUP; ++g) {
            float gm = s[g * 8];
#pragma unroll
            for (int q = 1; q < 8; ++q) gm = fmaxf(gm, s[g * 8 + q]);
            gs[g] = gm;
        }
        // top-3 groups, strict > => lowest index on ties (matches lax.top_k)
        unsigned gmask = 0;
        for (int r = 0; r < TOPKG; ++r) {
            int bg = 0; float bv = -INFINITY;
#pragma unroll
            for (int g = 0; g < NGROUP; ++g) {
                bool avail = !((gmask >> g) & 1);
                if (avail && gs[g] > bv) { bv = gs[g]; bg = g; }
            }
            gmask |= 1u << bg;
        }
        // top-6 experts over masked scores (masked -> 0.0, same as reference)
        unsigned long long chosen = 0ull;
        const int tok = row0 + t;
        for (int k = 0; k < TOPK; ++k) {
            int be = 0; float bv = -INFINITY;
#pragma unroll
            for (int e = 0; e < NEXP; ++e) {
                float v = ((gmask >> (e >> 3)) & 1u) ? s[e] : 0.f;
                bool avail = !((chosen >> e) & 1ull);
                if (avail && v > bv) { bv = v; be = e; }
            }
            chosen |= 1ull << be;
            out[(size_t)tok * TOPK + k] = (float)be;                 // idx as f32
            out[(size_t)half_out + (size_t)tok * TOPK + k] = bv;     // weight
        }
    }
}

extern "C" void kernel_launch(void* const* d_in, const int* in_sizes, int n_in,
                              void* d_out, int out_size, void* d_ws, size_t ws_size,
                              hipStream_t stream)
{
    const float* x = (const float*)d_in[0];
    const float* w = (const float*)d_in[1];
    float* out = (float*)d_out;
    const int half_out = out_size / 2;   // 98304 = 16384*6

    dim3 grid(TOKENS / MBLK);            // 1024 blocks -> 4 blocks/CU
    dim3 block(256);
    moe_gate_kernel<<<grid, block, 0, stream>>>(x, w, out, half_out);
}